// Round 1
// baseline (364.156 us; speedup 1.0000x reference)
//
#include <hip/hip_runtime.h>

#define NN 50000
#define NE 800000
#define DIN 128
#define DHID 256
#define MAXDEG 128   // Binomial(800k,1/50k): mean 16, sigma 4; 128 = 28 sigma

typedef __bf16 bf16x8 __attribute__((ext_vector_type(8)));
typedef float f32x4 __attribute__((ext_vector_type(4)));

static __device__ __forceinline__ unsigned short f2bf(float f) {
    unsigned u = __float_as_uint(f);
    unsigned r = 0x7fffu + ((u >> 16) & 1u);
    return (unsigned short)((u + r) >> 16);
}
static __device__ __forceinline__ float blo(unsigned u) { return __uint_as_float(u << 16); }
static __device__ __forceinline__ float bhi(unsigned u) { return __uint_as_float(u & 0xffff0000u); }

// ---------------- bucket build (fixed-stride buckets, x8 edge ILP) ----------------

__global__ void bucket_kernel(const int* __restrict__ src, const int* __restrict__ dst,
                              int* __restrict__ cnt, int* __restrict__ srcs, int E) {
    int i8 = (blockIdx.x * blockDim.x + threadIdx.x) * 8;
    if (i8 >= E) return;
    int4 da = *(const int4*)&dst[i8];
    int4 db = *(const int4*)&dst[i8 + 4];
    int4 sa = *(const int4*)&src[i8];
    int4 sb = *(const int4*)&src[i8 + 4];
    int t0 = atomicAdd(&cnt[da.x], 1);
    int t1 = atomicAdd(&cnt[da.y], 1);
    int t2 = atomicAdd(&cnt[da.z], 1);
    int t3 = atomicAdd(&cnt[da.w], 1);
    int t4 = atomicAdd(&cnt[db.x], 1);
    int t5 = atomicAdd(&cnt[db.y], 1);
    int t6 = atomicAdd(&cnt[db.z], 1);
    int t7 = atomicAdd(&cnt[db.w], 1);
    if (t0 < MAXDEG) srcs[(size_t)da.x * MAXDEG + t0] = sa.x;
    if (t1 < MAXDEG) srcs[(size_t)da.y * MAXDEG + t1] = sa.y;
    if (t2 < MAXDEG) srcs[(size_t)da.z * MAXDEG + t2] = sa.z;
    if (t3 < MAXDEG) srcs[(size_t)da.w * MAXDEG + t3] = sa.w;
    if (t4 < MAXDEG) srcs[(size_t)db.x * MAXDEG + t4] = sb.x;
    if (t5 < MAXDEG) srcs[(size_t)db.y * MAXDEG + t5] = sb.y;
    if (t6 < MAXDEG) srcs[(size_t)db.z * MAXDEG + t6] = sb.z;
    if (t7 < MAXDEG) srcs[(size_t)db.w * MAXDEG + t7] = sb.w;
}

// ---------------- prep: x fp32->bf16, zero cnt[], all 5 weights fp32->bf16 transposed ----------------

__global__ void prep_kernel(const float* __restrict__ x, unsigned short* __restrict__ xb,
                            int* __restrict__ cnt,
                            const float* __restrict__ W1_0, const float* __restrict__ W2_0,
                            const float* __restrict__ W1_1, const float* __restrict__ W2_1,
                            const float* __restrict__ Wo,
                            unsigned short* __restrict__ w10t, unsigned short* __restrict__ w20t,
                            unsigned short* __restrict__ w11t, unsigned short* __restrict__ w21t,
                            unsigned short* __restrict__ wot) {
    int i = blockIdx.x * blockDim.x + threadIdx.x;
    if (i < NN) cnt[i] = 0;
    if (i < 262144) {
        const float* W; unsigned short* Wt; int K, N, idx;
        if (i < 32768)        { W = W1_0; Wt = w10t; K = 128; N = 256; idx = i; }
        else if (i < 98304)   { W = W2_0; Wt = w20t; K = 256; N = 256; idx = i - 32768; }
        else if (i < 163840)  { W = W1_1; Wt = w11t; K = 256; N = 256; idx = i - 98304; }
        else if (i < 229376)  { W = W2_1; Wt = w21t; K = 256; N = 256; idx = i - 163840; }
        else                  { W = Wo;   Wt = wot;  K = 256; N = 128; idx = i - 229376; }
        int k = idx / N;
        int n = idx - k * N;
        Wt[(size_t)n * K + k] = f2bf(W[idx]);
    }
    if (i * 4 < NN * DIN) {
        float4 v = *(const float4*)(x + (size_t)i * 4);
        ushort4 o;
        o.x = f2bf(v.x); o.y = f2bf(v.y); o.z = f2bf(v.z); o.w = f2bf(v.w);
        *(ushort4*)(xb + (size_t)i * 4) = o;
    }
}

// ---------------- aggregation: multi-node per wave, 16B gathers ----------------
// D=128: 4 nodes/wave (16 lanes x uint4 = 256B row); D=256: 2 nodes/wave (32 x uint4).
// out[n] = (1+eps)*x[n] + sum_{s in N(n)} x[s]; fp32 accum.

template <int D>
__global__ void agg_bf16_kernel(const unsigned short* __restrict__ x, const int* __restrict__ cnt,
                                const int* __restrict__ srcs, const float* __restrict__ eps_p,
                                unsigned short* __restrict__ out, int n) {
    constexpr int G = (D == 128) ? 4 : 2;   // nodes per wave
    constexpr int L = 64 / G;               // lanes per node
    constexpr int RQ = D / 8;               // uint4 per row
    int tid = blockIdx.x * blockDim.x + threadIdx.x;
    int wid = tid >> 6;
    int lane = threadIdx.x & 63;
    int group = lane / L;
    int li = lane % L;
    int node = wid * G + group;
    if (node >= n) return;
    int deg = cnt[node]; if (deg > MAXDEG) deg = MAXDEG;
    const int* sp = srcs + (size_t)node * MAXDEG;
    const uint4* xp = (const uint4*)x;
    float e = 1.0f + eps_p[0];

    float a[8], b[8];
    #pragma unroll
    for (int j = 0; j < 8; j++) { a[j] = 0.f; b[j] = 0.f; }

    int i = 0;
    for (; i + 4 <= deg; i += 4) {
        int4 s = *(const int4*)&sp[i];
        uint4 v0 = xp[(size_t)s.x * RQ + li];
        uint4 v1 = xp[(size_t)s.y * RQ + li];
        uint4 v2 = xp[(size_t)s.z * RQ + li];
        uint4 v3 = xp[(size_t)s.w * RQ + li];
        a[0] += blo(v0.x); a[1] += bhi(v0.x); a[2] += blo(v0.y); a[3] += bhi(v0.y);
        a[4] += blo(v0.z); a[5] += bhi(v0.z); a[6] += blo(v0.w); a[7] += bhi(v0.w);
        b[0] += blo(v1.x); b[1] += bhi(v1.x); b[2] += blo(v1.y); b[3] += bhi(v1.y);
        b[4] += blo(v1.z); b[5] += bhi(v1.z); b[6] += blo(v1.w); b[7] += bhi(v1.w);
        a[0] += blo(v2.x); a[1] += bhi(v2.x); a[2] += blo(v2.y); a[3] += bhi(v2.y);
        a[4] += blo(v2.z); a[5] += bhi(v2.z); a[6] += blo(v2.w); a[7] += bhi(v2.w);
        b[0] += blo(v3.x); b[1] += bhi(v3.x); b[2] += blo(v3.y); b[3] += bhi(v3.y);
        b[4] += blo(v3.z); b[5] += bhi(v3.z); b[6] += blo(v3.w); b[7] += bhi(v3.w);
    }
    for (; i < deg; i++) {
        uint4 v = xp[(size_t)sp[i] * RQ + li];
        a[0] += blo(v.x); a[1] += bhi(v.x); a[2] += blo(v.y); a[3] += bhi(v.y);
        a[4] += blo(v.z); a[5] += bhi(v.z); a[6] += blo(v.w); a[7] += bhi(v.w);
    }
    uint4 xv = xp[(size_t)node * RQ + li];
    a[0] += b[0] + e * blo(xv.x); a[1] += b[1] + e * bhi(xv.x);
    a[2] += b[2] + e * blo(xv.y); a[3] += b[3] + e * bhi(xv.y);
    a[4] += b[4] + e * blo(xv.z); a[5] += b[5] + e * bhi(xv.z);
    a[6] += b[6] + e * blo(xv.w); a[7] += b[7] + e * bhi(xv.w);
    uint4 o;
    o.x = (unsigned)f2bf(a[0]) | ((unsigned)f2bf(a[1]) << 16);
    o.y = (unsigned)f2bf(a[2]) | ((unsigned)f2bf(a[3]) << 16);
    o.z = (unsigned)f2bf(a[4]) | ((unsigned)f2bf(a[5]) << 16);
    o.w = (unsigned)f2bf(a[6]) | ((unsigned)f2bf(a[7]) << 16);
    ((uint4*)out)[(size_t)node * RQ + li] = o;
}

// ---------------- fused MLP v3: 32-row M-tiles for 2x grid parallelism ----------------
// R0 counters showed mlp_fused latency-bound (MfmaUtil 9.5%, VALUBusy 17%, HBM 7.8%,
// Occupancy 14%): grid 782 blocks / 3128 waves can't fill 8192 wave slots, and
// mlp0==mlp1 duration despite 1.67x FLOPs confirms latency not throughput. v3 halves
// the M-tile 64->32 rows: grid 782->1563 blocks, LDS 32->16KB, acc[2][4] (~-30 VGPR).
// Same per-element accumulation order => bit-identical numerics.
// C = [relu(A@W1+b1)@W2+b2] (@Wo+bo if THREE). Weights pre-transposed [N][K] bf16,
// fully L2-resident (832KB total). ks-OUTER loops load a 4-frag W window per step;
// acc carried across the full K-reduction. Single 16KB H buffer: THREE defers phase-2
// epilogue in acc until one barrier, then overwrites H in place. MFMA swapped operands
// (bw, af): lane = C-row l16, regs = 4 consecutive C-cols. XOR chunk swizzle.

template <int K1, int THREE>
__global__ __launch_bounds__(256) void mlp_fused(
        const unsigned short* __restrict__ A,
        const unsigned short* __restrict__ W1t, const float* __restrict__ b1,
        const unsigned short* __restrict__ W2t, const float* __restrict__ b2,
        const unsigned short* __restrict__ W3t, const float* __restrict__ b3,
        unsigned short* __restrict__ Cb, float* __restrict__ Cf, int M) {
    constexpr int NKS1 = K1 / 32;
    constexpr int JT = 2;                        // 16-row fragments per block (32 rows)
    __shared__ __align__(16) unsigned short H[32 * 256];   // 16KB

    const int lane = threadIdx.x & 63;
    const int w = threadIdx.x >> 6;      // n-slice
    const int quad = lane >> 4;
    const int l16 = lane & 15;
    const size_t rowbase = (size_t)blockIdx.x * 32;

    f32x4 acc[JT][4];

    // ---- phase 1: acc = A @ W1 (stream W1) ----
    #pragma unroll
    for (int j = 0; j < JT; j++)
        #pragma unroll
        for (int nt = 0; nt < 4; nt++) acc[j][nt] = (f32x4)(0.f);
    #pragma unroll 2
    for (int ks = 0; ks < NKS1; ks++) {
        bf16x8 bw[4];
        #pragma unroll
        for (int nt = 0; nt < 4; nt++)
            bw[nt] = *(const bf16x8*)&W1t[(size_t)(w * 64 + nt * 16 + l16) * K1 + ks * 32 + quad * 8];
        #pragma unroll
        for (int j = 0; j < JT; j++) {
            bf16x8 af = *(const bf16x8*)&A[(rowbase + j * 16 + l16) * K1 + ks * 32 + quad * 8];
            #pragma unroll
            for (int nt = 0; nt < 4; nt++)
                acc[j][nt] = __builtin_amdgcn_mfma_f32_16x16x32_bf16(bw[nt], af, acc[j][nt], 0, 0, 0);
        }
    }
    {   // epilogue 1: bias + relu -> H (swizzled)
        f32x4 bvv[4];
        #pragma unroll
        for (int nt = 0; nt < 4; nt++)
            bvv[nt] = *(const f32x4*)&b1[w * 64 + nt * 16 + quad * 4];
        #pragma unroll
        for (int j = 0; j < JT; j++) {
            int r = j * 16 + l16;
            #pragma unroll
            for (int nt = 0; nt < 4; nt++) {
                f32x4 v = acc[j][nt] + bvv[nt];
                v[0] = fmaxf(v[0], 0.f); v[1] = fmaxf(v[1], 0.f);
                v[2] = fmaxf(v[2], 0.f); v[3] = fmaxf(v[3], 0.f);
                int c = w * 8 + nt * 2 + (quad >> 1);
                int cs = c ^ (r & 7);
                uint2 o;
                o.x = (unsigned)f2bf(v[0]) | ((unsigned)f2bf(v[1]) << 16);
                o.y = (unsigned)f2bf(v[2]) | ((unsigned)f2bf(v[3]) << 16);
                *(uint2*)&H[r * 256 + cs * 8 + (quad & 1) * 4] = o;
            }
        }
    }
    __syncthreads();

    // ---- phase 2: acc = H @ W2 (stream W2, K=256) ----
    #pragma unroll
    for (int j = 0; j < JT; j++)
        #pragma unroll
        for (int nt = 0; nt < 4; nt++) acc[j][nt] = (f32x4)(0.f);
    #pragma unroll 2
    for (int ks = 0; ks < 8; ks++) {
        bf16x8 bw[4];
        #pragma unroll
        for (int nt = 0; nt < 4; nt++)
            bw[nt] = *(const bf16x8*)&W2t[(size_t)(w * 64 + nt * 16 + l16) * 256 + ks * 32 + quad * 8];
        #pragma unroll
        for (int j = 0; j < JT; j++) {
            int r = j * 16 + l16;
            int cs = (ks * 4 + quad) ^ (r & 7);
            bf16x8 af = *(const bf16x8*)&H[r * 256 + cs * 8];
            #pragma unroll
            for (int nt = 0; nt < 4; nt++)
                acc[j][nt] = __builtin_amdgcn_mfma_f32_16x16x32_bf16(bw[nt], af, acc[j][nt], 0, 0, 0);
        }
    }
    {
        f32x4 bvv[4];
        #pragma unroll
        for (int nt = 0; nt < 4; nt++)
            bvv[nt] = *(const f32x4*)&b2[w * 64 + nt * 16 + quad * 4];
        if constexpr (!THREE) {
            #pragma unroll
            for (int j = 0; j < JT; j++) {
                size_t gm = rowbase + j * 16 + l16;
                if (gm < (size_t)M) {
                    #pragma unroll
                    for (int nt = 0; nt < 4; nt++) {
                        f32x4 v = acc[j][nt] + bvv[nt];
                        uint2 o;
                        o.x = (unsigned)f2bf(v[0]) | ((unsigned)f2bf(v[1]) << 16);
                        o.y = (unsigned)f2bf(v[2]) | ((unsigned)f2bf(v[3]) << 16);
                        *(uint2*)&Cb[gm * 256 + w * 64 + nt * 16 + quad * 4] = o;
                    }
                }
            }
        } else {
            __syncthreads();   // all H reads complete before in-place overwrite
            #pragma unroll
            for (int j = 0; j < JT; j++) {
                int r = j * 16 + l16;
                #pragma unroll
                for (int nt = 0; nt < 4; nt++) {
                    f32x4 v = acc[j][nt] + bvv[nt];
                    int c = w * 8 + nt * 2 + (quad >> 1);
                    int cs = c ^ (r & 7);
                    uint2 o;
                    o.x = (unsigned)f2bf(v[0]) | ((unsigned)f2bf(v[1]) << 16);
                    o.y = (unsigned)f2bf(v[2]) | ((unsigned)f2bf(v[3]) << 16);
                    *(uint2*)&H[r * 256 + cs * 8 + (quad & 1) * 4] = o;
                }
            }
            __syncthreads();
        }
    }

    // ---- phase 3 (THREE only): out = H @ Wo + bo (N=128, fp32) ----
    if constexpr (THREE) {
        f32x4 acc3[JT][2];
        #pragma unroll
        for (int j = 0; j < JT; j++)
            #pragma unroll
            for (int nt = 0; nt < 2; nt++) acc3[j][nt] = (f32x4)(0.f);
        #pragma unroll 2
        for (int ks = 0; ks < 8; ks++) {
            bf16x8 bw[2];
            #pragma unroll
            for (int nt = 0; nt < 2; nt++)
                bw[nt] = *(const bf16x8*)&W3t[(size_t)(w * 32 + nt * 16 + l16) * 256 + ks * 32 + quad * 8];
            #pragma unroll
            for (int j = 0; j < JT; j++) {
                int r = j * 16 + l16;
                int cs = (ks * 4 + quad) ^ (r & 7);
                bf16x8 af = *(const bf16x8*)&H[r * 256 + cs * 8];
                #pragma unroll
                for (int nt = 0; nt < 2; nt++)
                    acc3[j][nt] = __builtin_amdgcn_mfma_f32_16x16x32_bf16(bw[nt], af, acc3[j][nt], 0, 0, 0);
            }
        }
        f32x4 bv3[2];
        #pragma unroll
        for (int nt = 0; nt < 2; nt++)
            bv3[nt] = *(const f32x4*)&b3[w * 32 + nt * 16 + quad * 4];
        #pragma unroll
        for (int j = 0; j < JT; j++) {
            size_t gm = rowbase + j * 16 + l16;
            if (gm < (size_t)M) {
                #pragma unroll
                for (int nt = 0; nt < 2; nt++) {
                    f32x4 v = acc3[j][nt] + bv3[nt];
                    *(f32x4*)&Cf[gm * 128 + w * 32 + nt * 16 + quad * 4] = v;
                }
            }
        }
    }
}

// ---------------- launch ----------------

static inline size_t align256(size_t v) { return (v + 255) & ~(size_t)255; }

extern "C" void kernel_launch(void* const* d_in, const int* in_sizes, int n_in,
                              void* d_out, int out_size, void* d_ws, size_t ws_size,
                              hipStream_t stream) {
    const float* x        = (const float*)d_in[0];
    const int*   ei       = (const int*)d_in[1];
    const float* eps0     = (const float*)d_in[2];
    const float* W1_0     = (const float*)d_in[3];
    const float* b1_0     = (const float*)d_in[4];
    const float* W2_0     = (const float*)d_in[5];
    const float* b2_0     = (const float*)d_in[6];
    const float* eps1     = (const float*)d_in[7];
    const float* W1_1     = (const float*)d_in[8];
    const float* b1_1     = (const float*)d_in[9];
    const float* W2_1     = (const float*)d_in[10];
    const float* b2_1     = (const float*)d_in[11];
    const float* Wo       = (const float*)d_in[12];
    const float* bo       = (const float*)d_in[13];
    float* out            = (float*)d_out;

    const int* srcE = ei;
    const int* dstE = ei + NE;

    char* p = (char*)d_ws;
    size_t o = 0;
    int* cnt  = (int*)(p + o); o = align256(o + (size_t)NN * 4);
    int* srcs = (int*)(p + o); o = align256(o + (size_t)NN * MAXDEG * 4);
    unsigned short* xb   = (unsigned short*)(p + o); o = align256(o + (size_t)NN * DIN * 2);
    unsigned short* w10t = (unsigned short*)(p + o); o = align256(o + (size_t)DHID * DIN * 2);
    unsigned short* w20t = (unsigned short*)(p + o); o = align256(o + (size_t)DHID * DHID * 2);
    unsigned short* w11t = (unsigned short*)(p + o); o = align256(o + (size_t)DHID * DHID * 2);
    unsigned short* w21t = (unsigned short*)(p + o); o = align256(o + (size_t)DHID * DHID * 2);
    unsigned short* wot  = (unsigned short*)(p + o); o = align256(o + (size_t)DIN * DHID * 2);
    unsigned short* bufA = (unsigned short*)(p + o); o = align256(o + (size_t)NN * DHID * 2 + 65536);
    unsigned short* bufB = (unsigned short*)(p + o); o = align256(o + (size_t)NN * DHID * 2 + 65536);
    // +64KB pads: mlp_fused phase-1 last-block A over-read (16 rows x 512B max)

    prep_kernel<<<(NN * DIN / 4 + 255) / 256, 256, 0, stream>>>(
        x, xb, cnt, W1_0, W2_0, W1_1, W2_1, Wo, w10t, w20t, w11t, w21t, wot);
    bucket_kernel<<<(NE / 8 + 255) / 256, 256, 0, stream>>>(srcE, dstE, cnt, srcs, NE);

    int aggBlocks128 = ((NN + 3) / 4 + 3) / 4;   // 4 nodes/wave, 4 waves/block
    int aggBlocks256 = ((NN + 1) / 2 + 3) / 4;   // 2 nodes/wave
    int mlpBlocks = (NN + 31) / 32;              // 1563 (v3: 32-row tiles, 2x grid)

    // layer 0:  xb --agg--> bufA (D=128) --mlp0--> bufB (D=256)
    agg_bf16_kernel<DIN><<<aggBlocks128, 256, 0, stream>>>(xb, cnt, srcs, eps0, bufA, NN);
    mlp_fused<128, 0><<<mlpBlocks, 256, 0, stream>>>(
        bufA, w10t, b1_0, w20t, b2_0, nullptr, nullptr, bufB, nullptr, NN);

    // layer 1 + out:  bufB --agg--> bufA (D=256) --mlp1+o--> out (fp32)
    agg_bf16_kernel<DHID><<<aggBlocks256, 256, 0, stream>>>(bufB, cnt, srcs, eps1, bufA, NN);
    mlp_fused<256, 1><<<mlpBlocks, 256, 0, stream>>>(
        bufA, w11t, b1_1, w21t, b2_1, wot, bo, nullptr, out, NN);
}

// Round 2
// 331.960 us; speedup vs baseline: 1.0970x; 1.0970x over previous
//
#include <hip/hip_runtime.h>

#define NN 50000
#define NE 800000
#define DIN 128
#define DHID 256
#define MAXDEG 128   // Binomial(800k,1/50k): mean 16, sigma 4; 128 = 28 sigma

typedef __bf16 bf16x8 __attribute__((ext_vector_type(8)));
typedef float f32x4 __attribute__((ext_vector_type(4)));

static __device__ __forceinline__ unsigned short f2bf(float f) {
    unsigned u = __float_as_uint(f);
    unsigned r = 0x7fffu + ((u >> 16) & 1u);
    return (unsigned short)((u + r) >> 16);
}
static __device__ __forceinline__ float blo(unsigned u) { return __uint_as_float(u << 16); }
static __device__ __forceinline__ float bhi(unsigned u) { return __uint_as_float(u & 0xffff0000u); }

// ---------------- bucket build (fixed-stride buckets, x8 edge ILP) ----------------

__global__ void bucket_kernel(const int* __restrict__ src, const int* __restrict__ dst,
                              int* __restrict__ cnt, int* __restrict__ srcs, int E) {
    int i8 = (blockIdx.x * blockDim.x + threadIdx.x) * 8;
    if (i8 >= E) return;
    int4 da = *(const int4*)&dst[i8];
    int4 db = *(const int4*)&dst[i8 + 4];
    int4 sa = *(const int4*)&src[i8];
    int4 sb = *(const int4*)&src[i8 + 4];
    int t0 = atomicAdd(&cnt[da.x], 1);
    int t1 = atomicAdd(&cnt[da.y], 1);
    int t2 = atomicAdd(&cnt[da.z], 1);
    int t3 = atomicAdd(&cnt[da.w], 1);
    int t4 = atomicAdd(&cnt[db.x], 1);
    int t5 = atomicAdd(&cnt[db.y], 1);
    int t6 = atomicAdd(&cnt[db.z], 1);
    int t7 = atomicAdd(&cnt[db.w], 1);
    if (t0 < MAXDEG) srcs[(size_t)da.x * MAXDEG + t0] = sa.x;
    if (t1 < MAXDEG) srcs[(size_t)da.y * MAXDEG + t1] = sa.y;
    if (t2 < MAXDEG) srcs[(size_t)da.z * MAXDEG + t2] = sa.z;
    if (t3 < MAXDEG) srcs[(size_t)da.w * MAXDEG + t3] = sa.w;
    if (t4 < MAXDEG) srcs[(size_t)db.x * MAXDEG + t4] = sb.x;
    if (t5 < MAXDEG) srcs[(size_t)db.y * MAXDEG + t5] = sb.y;
    if (t6 < MAXDEG) srcs[(size_t)db.z * MAXDEG + t6] = sb.z;
    if (t7 < MAXDEG) srcs[(size_t)db.w * MAXDEG + t7] = sb.w;
}

// ---------------- prep: x fp32->bf16, zero cnt[], all 5 weights fp32->bf16 transposed ----------------

__global__ void prep_kernel(const float* __restrict__ x, unsigned short* __restrict__ xb,
                            int* __restrict__ cnt,
                            const float* __restrict__ W1_0, const float* __restrict__ W2_0,
                            const float* __restrict__ W1_1, const float* __restrict__ W2_1,
                            const float* __restrict__ Wo,
                            unsigned short* __restrict__ w10t, unsigned short* __restrict__ w20t,
                            unsigned short* __restrict__ w11t, unsigned short* __restrict__ w21t,
                            unsigned short* __restrict__ wot) {
    int i = blockIdx.x * blockDim.x + threadIdx.x;
    if (i < NN) cnt[i] = 0;
    if (i < 262144) {
        const float* W; unsigned short* Wt; int K, N, idx;
        if (i < 32768)        { W = W1_0; Wt = w10t; K = 128; N = 256; idx = i; }
        else if (i < 98304)   { W = W2_0; Wt = w20t; K = 256; N = 256; idx = i - 32768; }
        else if (i < 163840)  { W = W1_1; Wt = w11t; K = 256; N = 256; idx = i - 98304; }
        else if (i < 229376)  { W = W2_1; Wt = w21t; K = 256; N = 256; idx = i - 163840; }
        else                  { W = Wo;   Wt = wot;  K = 256; N = 128; idx = i - 229376; }
        int k = idx / N;
        int n = idx - k * N;
        Wt[(size_t)n * K + k] = f2bf(W[idx]);
    }
    if (i * 4 < NN * DIN) {
        float4 v = *(const float4*)(x + (size_t)i * 4);
        ushort4 o;
        o.x = f2bf(v.x); o.y = f2bf(v.y); o.z = f2bf(v.z); o.w = f2bf(v.w);
        *(ushort4*)(xb + (size_t)i * 4) = o;
    }
}

// ---------------- aggregation: multi-node per wave, 16B gathers, 8-deep MLP ----------------
// D=128: 4 nodes/wave (16 lanes x uint4 = 256B row); D=256: 2 nodes/wave (32 x uint4).
// out[n] = (1+eps)*x[n] + sum_{s in N(n)} x[s]; fp32 accum.
// R2: deg-loop unrolled 8-deep (8 independent row-gathers in flight per node-group;
// R1's 4-deep left the ~400-900cy gather latency exposed every 4 loads). Accumulation
// statement order matches two consecutive R0 4-batches exactly -> bit-identical output.

template <int D>
__global__ void agg_bf16_kernel(const unsigned short* __restrict__ x, const int* __restrict__ cnt,
                                const int* __restrict__ srcs, const float* __restrict__ eps_p,
                                unsigned short* __restrict__ out, int n) {
    constexpr int G = (D == 128) ? 4 : 2;   // nodes per wave
    constexpr int L = 64 / G;               // lanes per node
    constexpr int RQ = D / 8;               // uint4 per row
    int tid = blockIdx.x * blockDim.x + threadIdx.x;
    int wid = tid >> 6;
    int lane = threadIdx.x & 63;
    int group = lane / L;
    int li = lane % L;
    int node = wid * G + group;
    if (node >= n) return;
    int deg = cnt[node]; if (deg > MAXDEG) deg = MAXDEG;
    const int* sp = srcs + (size_t)node * MAXDEG;
    const uint4* xp = (const uint4*)x;
    float e = 1.0f + eps_p[0];

    float a[8], b[8];
    #pragma unroll
    for (int j = 0; j < 8; j++) { a[j] = 0.f; b[j] = 0.f; }

    int i = 0;
    for (; i + 8 <= deg; i += 8) {
        int4 s0 = *(const int4*)&sp[i];
        int4 s1 = *(const int4*)&sp[i + 4];
        uint4 v0 = xp[(size_t)s0.x * RQ + li];
        uint4 v1 = xp[(size_t)s0.y * RQ + li];
        uint4 v2 = xp[(size_t)s0.z * RQ + li];
        uint4 v3 = xp[(size_t)s0.w * RQ + li];
        uint4 v4 = xp[(size_t)s1.x * RQ + li];
        uint4 v5 = xp[(size_t)s1.y * RQ + li];
        uint4 v6 = xp[(size_t)s1.z * RQ + li];
        uint4 v7 = xp[(size_t)s1.w * RQ + li];
        a[0] += blo(v0.x); a[1] += bhi(v0.x); a[2] += blo(v0.y); a[3] += bhi(v0.y);
        a[4] += blo(v0.z); a[5] += bhi(v0.z); a[6] += blo(v0.w); a[7] += bhi(v0.w);
        b[0] += blo(v1.x); b[1] += bhi(v1.x); b[2] += blo(v1.y); b[3] += bhi(v1.y);
        b[4] += blo(v1.z); b[5] += bhi(v1.z); b[6] += blo(v1.w); b[7] += bhi(v1.w);
        a[0] += blo(v2.x); a[1] += bhi(v2.x); a[2] += blo(v2.y); a[3] += bhi(v2.y);
        a[4] += blo(v2.z); a[5] += bhi(v2.z); a[6] += blo(v2.w); a[7] += bhi(v2.w);
        b[0] += blo(v3.x); b[1] += bhi(v3.x); b[2] += blo(v3.y); b[3] += bhi(v3.y);
        b[4] += blo(v3.z); b[5] += bhi(v3.z); b[6] += blo(v3.w); b[7] += bhi(v3.w);
        a[0] += blo(v4.x); a[1] += bhi(v4.x); a[2] += blo(v4.y); a[3] += bhi(v4.y);
        a[4] += blo(v4.z); a[5] += bhi(v4.z); a[6] += blo(v4.w); a[7] += bhi(v4.w);
        b[0] += blo(v5.x); b[1] += bhi(v5.x); b[2] += blo(v5.y); b[3] += bhi(v5.y);
        b[4] += blo(v5.z); b[5] += bhi(v5.z); b[6] += blo(v5.w); b[7] += bhi(v5.w);
        a[0] += blo(v6.x); a[1] += bhi(v6.x); a[2] += blo(v6.y); a[3] += bhi(v6.y);
        a[4] += blo(v6.z); a[5] += bhi(v6.z); a[6] += blo(v6.w); a[7] += bhi(v6.w);
        b[0] += blo(v7.x); b[1] += bhi(v7.x); b[2] += blo(v7.y); b[3] += bhi(v7.y);
        b[4] += blo(v7.z); b[5] += bhi(v7.z); b[6] += blo(v7.w); b[7] += bhi(v7.w);
    }
    for (; i + 4 <= deg; i += 4) {
        int4 s = *(const int4*)&sp[i];
        uint4 v0 = xp[(size_t)s.x * RQ + li];
        uint4 v1 = xp[(size_t)s.y * RQ + li];
        uint4 v2 = xp[(size_t)s.z * RQ + li];
        uint4 v3 = xp[(size_t)s.w * RQ + li];
        a[0] += blo(v0.x); a[1] += bhi(v0.x); a[2] += blo(v0.y); a[3] += bhi(v0.y);
        a[4] += blo(v0.z); a[5] += bhi(v0.z); a[6] += blo(v0.w); a[7] += bhi(v0.w);
        b[0] += blo(v1.x); b[1] += bhi(v1.x); b[2] += blo(v1.y); b[3] += bhi(v1.y);
        b[4] += blo(v1.z); b[5] += bhi(v1.z); b[6] += blo(v1.w); b[7] += bhi(v1.w);
        a[0] += blo(v2.x); a[1] += bhi(v2.x); a[2] += blo(v2.y); a[3] += bhi(v2.y);
        a[4] += blo(v2.z); a[5] += bhi(v2.z); a[6] += blo(v2.w); a[7] += bhi(v2.w);
        b[0] += blo(v3.x); b[1] += bhi(v3.x); b[2] += blo(v3.y); b[3] += bhi(v3.y);
        b[4] += blo(v3.z); b[5] += bhi(v3.z); b[6] += blo(v3.w); b[7] += bhi(v3.w);
    }
    for (; i < deg; i++) {
        uint4 v = xp[(size_t)sp[i] * RQ + li];
        a[0] += blo(v.x); a[1] += bhi(v.x); a[2] += blo(v.y); a[3] += bhi(v.y);
        a[4] += blo(v.z); a[5] += bhi(v.z); a[6] += blo(v.w); a[7] += bhi(v.w);
    }
    uint4 xv = xp[(size_t)node * RQ + li];
    a[0] += b[0] + e * blo(xv.x); a[1] += b[1] + e * bhi(xv.x);
    a[2] += b[2] + e * blo(xv.y); a[3] += b[3] + e * bhi(xv.y);
    a[4] += b[4] + e * blo(xv.z); a[5] += b[5] + e * bhi(xv.z);
    a[6] += b[6] + e * blo(xv.w); a[7] += b[7] + e * bhi(xv.w);
    uint4 o;
    o.x = (unsigned)f2bf(a[0]) | ((unsigned)f2bf(a[1]) << 16);
    o.y = (unsigned)f2bf(a[2]) | ((unsigned)f2bf(a[3]) << 16);
    o.z = (unsigned)f2bf(a[4]) | ((unsigned)f2bf(a[5]) << 16);
    o.w = (unsigned)f2bf(a[6]) | ((unsigned)f2bf(a[7]) << 16);
    ((uint4*)out)[(size_t)node * RQ + li] = o;
}

// ---------------- fused MLP v2 (reverted from v3): 64-row tiles ----------------
// R1 post-mortem: 32-row tiles doubled occupancy (14->32%) but duration ROSE 64->85.6us
// and MfmaUtil FELL 9.5->7.3% -- the limiter is total per-block weight streaming
// (W amortizes over M-rows/block), not per-block latency. 64-row tile is the verified
// best amortization point. C = [relu(A@W1+b1)@W2+b2] (@Wo+bo if THREE). Weights
// pre-transposed [N][K] bf16, L2-resident (832KB). ks-OUTER loops stream a 4-frag W
// window; acc[4][4] carried across full K. Single 32KB H buffer; THREE defers phase-2
// epilogue in acc until one barrier, then overwrites H in place. MFMA swapped operands
// (bw, af): lane = C-row l16, regs = 4 consecutive C-cols. XOR chunk swizzle.

template <int K1, int THREE>
__global__ __launch_bounds__(256) void mlp_fused(
        const unsigned short* __restrict__ A,
        const unsigned short* __restrict__ W1t, const float* __restrict__ b1,
        const unsigned short* __restrict__ W2t, const float* __restrict__ b2,
        const unsigned short* __restrict__ W3t, const float* __restrict__ b3,
        unsigned short* __restrict__ Cb, float* __restrict__ Cf, int M) {
    constexpr int NKS1 = K1 / 32;
    __shared__ __align__(16) unsigned short H[64 * 256];   // 32KB

    const int lane = threadIdx.x & 63;
    const int w = threadIdx.x >> 6;      // n-slice
    const int quad = lane >> 4;
    const int l16 = lane & 15;
    const size_t rowbase = (size_t)blockIdx.x * 64;

    f32x4 acc[4][4];

    // ---- phase 1: acc = A @ W1 (stream W1) ----
    #pragma unroll
    for (int j = 0; j < 4; j++)
        #pragma unroll
        for (int nt = 0; nt < 4; nt++) acc[j][nt] = (f32x4)(0.f);
    #pragma unroll 2
    for (int ks = 0; ks < NKS1; ks++) {
        bf16x8 bw[4];
        #pragma unroll
        for (int nt = 0; nt < 4; nt++)
            bw[nt] = *(const bf16x8*)&W1t[(size_t)(w * 64 + nt * 16 + l16) * K1 + ks * 32 + quad * 8];
        #pragma unroll
        for (int j = 0; j < 4; j++) {
            bf16x8 af = *(const bf16x8*)&A[(rowbase + j * 16 + l16) * K1 + ks * 32 + quad * 8];
            #pragma unroll
            for (int nt = 0; nt < 4; nt++)
                acc[j][nt] = __builtin_amdgcn_mfma_f32_16x16x32_bf16(bw[nt], af, acc[j][nt], 0, 0, 0);
        }
    }
    {   // epilogue 1: bias + relu -> H (swizzled)
        f32x4 bvv[4];
        #pragma unroll
        for (int nt = 0; nt < 4; nt++)
            bvv[nt] = *(const f32x4*)&b1[w * 64 + nt * 16 + quad * 4];
        #pragma unroll
        for (int j = 0; j < 4; j++) {
            int r = j * 16 + l16;
            #pragma unroll
            for (int nt = 0; nt < 4; nt++) {
                f32x4 v = acc[j][nt] + bvv[nt];
                v[0] = fmaxf(v[0], 0.f); v[1] = fmaxf(v[1], 0.f);
                v[2] = fmaxf(v[2], 0.f); v[3] = fmaxf(v[3], 0.f);
                int c = w * 8 + nt * 2 + (quad >> 1);
                int cs = c ^ (r & 7);
                uint2 o;
                o.x = (unsigned)f2bf(v[0]) | ((unsigned)f2bf(v[1]) << 16);
                o.y = (unsigned)f2bf(v[2]) | ((unsigned)f2bf(v[3]) << 16);
                *(uint2*)&H[r * 256 + cs * 8 + (quad & 1) * 4] = o;
            }
        }
    }
    __syncthreads();

    // ---- phase 2: acc = H @ W2 (stream W2, K=256) ----
    #pragma unroll
    for (int j = 0; j < 4; j++)
        #pragma unroll
        for (int nt = 0; nt < 4; nt++) acc[j][nt] = (f32x4)(0.f);
    #pragma unroll 2
    for (int ks = 0; ks < 8; ks++) {
        bf16x8 bw[4];
        #pragma unroll
        for (int nt = 0; nt < 4; nt++)
            bw[nt] = *(const bf16x8*)&W2t[(size_t)(w * 64 + nt * 16 + l16) * 256 + ks * 32 + quad * 8];
        #pragma unroll
        for (int j = 0; j < 4; j++) {
            int r = j * 16 + l16;
            int cs = (ks * 4 + quad) ^ (r & 7);
            bf16x8 af = *(const bf16x8*)&H[r * 256 + cs * 8];
            #pragma unroll
            for (int nt = 0; nt < 4; nt++)
                acc[j][nt] = __builtin_amdgcn_mfma_f32_16x16x32_bf16(bw[nt], af, acc[j][nt], 0, 0, 0);
        }
    }
    {
        f32x4 bvv[4];
        #pragma unroll
        for (int nt = 0; nt < 4; nt++)
            bvv[nt] = *(const f32x4*)&b2[w * 64 + nt * 16 + quad * 4];
        if constexpr (!THREE) {
            #pragma unroll
            for (int j = 0; j < 4; j++) {
                size_t gm = rowbase + j * 16 + l16;
                if (gm < (size_t)M) {
                    #pragma unroll
                    for (int nt = 0; nt < 4; nt++) {
                        f32x4 v = acc[j][nt] + bvv[nt];
                        uint2 o;
                        o.x = (unsigned)f2bf(v[0]) | ((unsigned)f2bf(v[1]) << 16);
                        o.y = (unsigned)f2bf(v[2]) | ((unsigned)f2bf(v[3]) << 16);
                        *(uint2*)&Cb[gm * 256 + w * 64 + nt * 16 + quad * 4] = o;
                    }
                }
            }
        } else {
            __syncthreads();   // all H reads complete before in-place overwrite
            #pragma unroll
            for (int j = 0; j < 4; j++) {
                int r = j * 16 + l16;
                #pragma unroll
                for (int nt = 0; nt < 4; nt++) {
                    f32x4 v = acc[j][nt] + bvv[nt];
                    int c = w * 8 + nt * 2 + (quad >> 1);
                    int cs = c ^ (r & 7);
                    uint2 o;
                    o.x = (unsigned)f2bf(v[0]) | ((unsigned)f2bf(v[1]) << 16);
                    o.y = (unsigned)f2bf(v[2]) | ((unsigned)f2bf(v[3]) << 16);
                    *(uint2*)&H[r * 256 + cs * 8 + (quad & 1) * 4] = o;
                }
            }
            __syncthreads();
        }
    }

    // ---- phase 3 (THREE only): out = H @ Wo + bo (N=128, fp32) ----
    if constexpr (THREE) {
        f32x4 acc3[4][2];
        #pragma unroll
        for (int j = 0; j < 4; j++)
            #pragma unroll
            for (int nt = 0; nt < 2; nt++) acc3[j][nt] = (f32x4)(0.f);
        #pragma unroll 2
        for (int ks = 0; ks < 8; ks++) {
            bf16x8 bw[2];
            #pragma unroll
            for (int nt = 0; nt < 2; nt++)
                bw[nt] = *(const bf16x8*)&W3t[(size_t)(w * 32 + nt * 16 + l16) * 256 + ks * 32 + quad * 8];
            #pragma unroll
            for (int j = 0; j < 4; j++) {
                int r = j * 16 + l16;
                int cs = (ks * 4 + quad) ^ (r & 7);
                bf16x8 af = *(const bf16x8*)&H[r * 256 + cs * 8];
                #pragma unroll
                for (int nt = 0; nt < 2; nt++)
                    acc3[j][nt] = __builtin_amdgcn_mfma_f32_16x16x32_bf16(bw[nt], af, acc3[j][nt], 0, 0, 0);
            }
        }
        f32x4 bv3[2];
        #pragma unroll
        for (int nt = 0; nt < 2; nt++)
            bv3[nt] = *(const f32x4*)&b3[w * 32 + nt * 16 + quad * 4];
        #pragma unroll
        for (int j = 0; j < 4; j++) {
            size_t gm = rowbase + j * 16 + l16;
            if (gm < (size_t)M) {
                #pragma unroll
                for (int nt = 0; nt < 2; nt++) {
                    f32x4 v = acc3[j][nt] + bv3[nt];
                    *(f32x4*)&Cf[gm * 128 + w * 32 + nt * 16 + quad * 4] = v;
                }
            }
        }
    }
}

// ---------------- launch ----------------

static inline size_t align256(size_t v) { return (v + 255) & ~(size_t)255; }

extern "C" void kernel_launch(void* const* d_in, const int* in_sizes, int n_in,
                              void* d_out, int out_size, void* d_ws, size_t ws_size,
                              hipStream_t stream) {
    const float* x        = (const float*)d_in[0];
    const int*   ei       = (const int*)d_in[1];
    const float* eps0     = (const float*)d_in[2];
    const float* W1_0     = (const float*)d_in[3];
    const float* b1_0     = (const float*)d_in[4];
    const float* W2_0     = (const float*)d_in[5];
    const float* b2_0     = (const float*)d_in[6];
    const float* eps1     = (const float*)d_in[7];
    const float* W1_1     = (const float*)d_in[8];
    const float* b1_1     = (const float*)d_in[9];
    const float* W2_1     = (const float*)d_in[10];
    const float* b2_1     = (const float*)d_in[11];
    const float* Wo       = (const float*)d_in[12];
    const float* bo       = (const float*)d_in[13];
    float* out            = (float*)d_out;

    const int* srcE = ei;
    const int* dstE = ei + NE;

    char* p = (char*)d_ws;
    size_t o = 0;
    int* cnt  = (int*)(p + o); o = align256(o + (size_t)NN * 4);
    int* srcs = (int*)(p + o); o = align256(o + (size_t)NN * MAXDEG * 4);
    unsigned short* xb   = (unsigned short*)(p + o); o = align256(o + (size_t)NN * DIN * 2);
    unsigned short* w10t = (unsigned short*)(p + o); o = align256(o + (size_t)DHID * DIN * 2);
    unsigned short* w20t = (unsigned short*)(p + o); o = align256(o + (size_t)DHID * DHID * 2);
    unsigned short* w11t = (unsigned short*)(p + o); o = align256(o + (size_t)DHID * DHID * 2);
    unsigned short* w21t = (unsigned short*)(p + o); o = align256(o + (size_t)DHID * DHID * 2);
    unsigned short* wot  = (unsigned short*)(p + o); o = align256(o + (size_t)DIN * DHID * 2);
    unsigned short* bufA = (unsigned short*)(p + o); o = align256(o + (size_t)NN * DHID * 2 + 65536);
    unsigned short* bufB = (unsigned short*)(p + o); o = align256(o + (size_t)NN * DHID * 2 + 65536);
    // +64KB pads: mlp_fused phase-1 last-block A over-read (47 rows x 512B max)

    prep_kernel<<<(NN * DIN / 4 + 255) / 256, 256, 0, stream>>>(
        x, xb, cnt, W1_0, W2_0, W1_1, W2_1, Wo, w10t, w20t, w11t, w21t, wot);
    bucket_kernel<<<(NE / 8 + 255) / 256, 256, 0, stream>>>(srcE, dstE, cnt, srcs, NE);

    int aggBlocks128 = ((NN + 3) / 4 + 3) / 4;   // 4 nodes/wave, 4 waves/block
    int aggBlocks256 = ((NN + 1) / 2 + 3) / 4;   // 2 nodes/wave
    int mlpBlocks = (NN + 63) / 64;              // 782

    // layer 0:  xb --agg--> bufA (D=128) --mlp0--> bufB (D=256)
    agg_bf16_kernel<DIN><<<aggBlocks128, 256, 0, stream>>>(xb, cnt, srcs, eps0, bufA, NN);
    mlp_fused<128, 0><<<mlpBlocks, 256, 0, stream>>>(
        bufA, w10t, b1_0, w20t, b2_0, nullptr, nullptr, bufB, nullptr, NN);

    // layer 1 + out:  bufB --agg--> bufA (D=256) --mlp1+o--> out (fp32)
    agg_bf16_kernel<DHID><<<aggBlocks256, 256, 0, stream>>>(bufB, cnt, srcs, eps1, bufA, NN);
    mlp_fused<256, 1><<<mlpBlocks, 256, 0, stream>>>(
        bufA, w11t, b1_1, w21t, b2_1, wot, bo, nullptr, out, NN);
}